// Round 8
// baseline (86.566 us; speedup 1.0000x reference)
//
#include <hip/hip_runtime.h>
#include <hip/hip_bf16.h>
#include <math.h>

typedef _Float16 half8  __attribute__((ext_vector_type(8)));
typedef _Float16 half4v __attribute__((ext_vector_type(4)));
typedef __fp16   fp16x2 __attribute__((ext_vector_type(2)));
typedef float    f32x4  __attribute__((ext_vector_type(4)));
typedef float    f32x16 __attribute__((ext_vector_type(16)));
typedef int      i32x2v __attribute__((ext_vector_type(2)));

#define DDIM 128
#define LQ   512
#define NKV  2048
#define NB   32
#define NIT  8

union U32H2 { unsigned u; fp16x2 h; };
union PW    { unsigned u[4]; half8 h; };

// permlane32_swap(a,b) -> ([a_lo|b_lo], [a_hi|b_hi])
__device__ __forceinline__ float xmax64(float v) {
  i32x2v r = __builtin_amdgcn_permlane32_swap(__float_as_int(v), __float_as_int(v), false, false);
  return fmaxf(__int_as_float(r[0]), __int_as_float(r[1]));
}
__device__ __forceinline__ float xsum64(float v) {
  i32x2v r = __builtin_amdgcn_permlane32_swap(__float_as_int(v), __float_as_int(v), false, false);
  return __int_as_float(r[0]) + __int_as_float(r[1]);
}

__device__ __forceinline__ void dma16(const void* g, void* l) {
  __builtin_amdgcn_global_load_lds(
      (const __attribute__((address_space(1))) unsigned int*)g,
      (__attribute__((address_space(3))) unsigned int*)l, 16, 0, 0);
}

// ---------------- prep: fism f32 -> K16 [b][kv][d] f16 and VT16 [b][d][kv] f16 ----------------
__global__ __launch_bounds__(256)
void prep(const float* __restrict__ fism, _Float16* __restrict__ K16,
          _Float16* __restrict__ VT16)
{
  __shared__ _Float16 T[64 * DDIM]; // [d][64kv], unit-swizzled: elem = d*64 + ((kv>>3)^(d&7))*8 + (kv&7)
  const int tid = threadIdx.x;
  const int bb  = blockIdx.x >> 5;
  const int kv0 = (blockIdx.x & 31) * 64;
  {
    const int r  = tid >> 2;
    const int cq = tid & 3;
    const float* src = fism + ((size_t)(bb*NKV + kv0 + r) * DDIM + cq*32);
    _Float16*    kd  = K16  + ((size_t)(bb*NKV + kv0 + r) * DDIM + cq*32);
    float4 v[8];
    #pragma unroll
    for (int k = 0; k < 8; ++k) v[k] = ((const float4*)src)[k];
    _Float16 h[32];
    #pragma unroll
    for (int k = 0; k < 8; ++k) {
      h[4*k+0] = (_Float16)v[k].x; h[4*k+1] = (_Float16)v[k].y;
      h[4*k+2] = (_Float16)v[k].z; h[4*k+3] = (_Float16)v[k].w;
    }
    #pragma unroll
    for (int k = 0; k < 4; ++k) ((half8*)kd)[k] = *(half8*)&h[8*k];
    #pragma unroll
    for (int j = 0; j < 32; ++j) {
      const int d = cq*32 + j;
      T[d*64 + (((r>>3) ^ (d&7))<<3) + (r&7)] = h[j];
    }
  }
  __syncthreads();
  {
    const int d  = tid >> 1;
    const int kh = tid & 1;
    _Float16* vd = VT16 + ((size_t)(bb*DDIM + d) * NKV + kv0 + kh*32);
    #pragma unroll
    for (int u = 0; u < 4; ++u) {
      const int k8 = kh*4 + u;
      ((half8*)vd)[u] = *(half8*)&T[d*64 + ((k8 ^ (d&7))<<3)];
    }
  }
}

// ---------------- main: 16 waves, DMA staging, in-register softmax ----------------
// POOL layout (bytes): Ksh [0,65536): 4 x [64row][16 units]; VTsh [65536,131072): 4 x [64dRow][16 units];
// Q16 [131072,147456): [64row][16 units]; statsA @147456 [4][2][32][4]f; statsB @151552.
#define QOFF   131072
#define SAOFF  147456
#define SBOFF  151552

__global__ __launch_bounds__(1024, 4)
void gattn(const float* __restrict__ seq, const _Float16* __restrict__ K16,
           const _Float16* __restrict__ VT16, float* __restrict__ out)
{
  __shared__ __align__(16) unsigned char POOL[155648];

  const int tid  = threadIdx.x;
  const int lane = tid & 63;
  const int wv   = tid >> 6;      // 0..15
  const int wq   = wv & 1;        // q-group (32 rows)
  const int kvp  = wv >> 1;       // 0..7 kv stream
  const int kvq  = kvp >> 1;      // quarter buffer 0..3
  const int ns   = kvp & 1;       // which 32-row half of the 64-chunk
  const int l31  = lane & 31;
  const int hi   = lane >> 5;

  const int swz = (blockIdx.x & 7) * 32 + (blockIdx.x >> 3);
  const int b   = swz >> 3;
  const int qb  = (swz & 7) * 64;

  const float* seqB = seq + (size_t)b * LQ * DDIM;
  float*       outB = out + (size_t)b * LQ * DDIM;
  const _Float16* K16b  = K16  + (size_t)b * NKV * DDIM;
  const _Float16* VT16b = VT16 + (size_t)b * DDIM * NKV;

  // ---- Q tile -> LDS f16, unit-swizzled (phys unit sp holds logical s = sp^(row&15)) ----
  {
    const int row = tid >> 4, sp = tid & 15;
    const int s = sp ^ (row & 15);
    const float* qsrc = seqB + (size_t)(qb + row) * DDIM + s*8;
    float4 a = ((const float4*)qsrc)[0], b2 = ((const float4*)qsrc)[1];
    _Float16 hq[8];
    hq[0]=(_Float16)a.x;  hq[1]=(_Float16)a.y;  hq[2]=(_Float16)a.z;  hq[3]=(_Float16)a.w;
    hq[4]=(_Float16)b2.x; hq[5]=(_Float16)b2.y; hq[6]=(_Float16)b2.z; hq[7]=(_Float16)b2.w;
    *(half8*)&POOL[QOFF + tid*16] = *(half8*)hq;
  }

  // ---- DMA source offsets (per lane, constant over t) ----
  // waves 0..7 stage K (unit = wv*512 + i*64 + lane of 4096), waves 8..15 stage VT.
  int off[8];
  const bool isK = (wv < 8);
  const int w8 = wv & 7;
  if (isK) {
    #pragma unroll
    for (int i = 0; i < 8; ++i) {
      const int unit = w8*512 + i*64 + lane;
      const int q = unit >> 10, row = (unit >> 4) & 63, sp = unit & 15;
      const int s = sp ^ (row & 15);
      off[i] = (q*512 + row)*128 + s*8;
    }
  } else {
    #pragma unroll
    for (int i = 0; i < 8; ++i) {
      const int unit = w8*512 + i*64 + lane;
      const int q = unit >> 10, dRow = (unit >> 4) & 63, sp = unit & 15;
      const int s = sp ^ (dRow & 15);
      const int d = dRow*2 + (s >> 3);
      off[i] = d*2048 + q*512 + (s & 7)*8;
    }
  }
  const _Float16* sbase = isK ? K16b : VT16b;
  const int tstride = isK ? 8192 : 64;
  const int ldsbase = (isK ? 0 : 65536) + w8*8192;

  auto stage = [&](int tt) {
    const _Float16* s0 = sbase + tt * tstride;
    #pragma unroll
    for (int i = 0; i < 8; ++i)
      dma16(s0 + off[i], &POOL[ldsbase + i*1024]);
  };

  f32x16 acc[4];
  #pragma unroll
  for (int dt = 0; dt < 4; ++dt)
    #pragma unroll
    for (int i = 0; i < 16; ++i) acc[dt][i] = 0.f;

  float m_run = -INFINITY, tmax = -INFINITY, S_run = 0.f;

  const int krow   = ns*32 + l31;
  const int kqbase = kvq*16384 + krow*256;
  const int kswz   = krow & 15;
  const int qrow   = wq*32 + l31;
  const int qbase  = QOFF + qrow*256;
  const int qswz   = qrow & 15;

  stage(0);   // prologue DMA (both K and VT groups)

  for (int t = 0; t < NIT; ++t) {
    __syncthreads();                       // barrier0: all DMA landed

    // ---- QK^T: A = K rows (m=kv local), B = Q (col=q). sv: row=kv32, col=q ----
    f32x16 sv;
    #pragma unroll
    for (int i = 0; i < 16; ++i) sv[i] = 0.f;
    #pragma unroll
    for (int g2 = 0; g2 < 2; ++g2) {
      half8 ka[4], qa[4];
      #pragma unroll
      for (int c2 = 0; c2 < 4; ++c2) {
        const int u = 2*(g2*4 + c2) + hi;
        ka[c2] = *(const half8*)&POOL[kqbase + ((u ^ kswz) << 4)];
        qa[c2] = *(const half8*)&POOL[qbase  + ((u ^ qswz) << 4)];
      }
      #pragma unroll
      for (int c2 = 0; c2 < 4; ++c2)
        sv = __builtin_amdgcn_mfma_f32_32x32x16_f16(ka[c2], qa[c2], sv, 0, 0, 0);
    }

    __syncthreads();                       // barrier1: K reads done
    if (isK && t + 1 < NIT) stage(t + 1);  // K-DMA hides under softmax+PV

    // ---- online power-softmax (lane-local, col=q) ----
    float m8[8];
    #pragma unroll
    for (int i = 0; i < 8; ++i) m8[i] = fmaxf(sv[i], sv[i+8]);
    #pragma unroll
    for (int st = 4; st > 0; st >>= 1)
      #pragma unroll
      for (int i = 0; i < st; ++i) m8[i] = fmaxf(m8[i], m8[i+st]);
    const float cmax = xmax64(m8[0]);
    tmax = fmaxf(tmax, cmax);
    if (__any(cmax > m_run + 8.f)) {
      const float mn = fmaxf(m_run, cmax);
      const float sc = __expf(m_run - mn);
      S_run *= sc;
      m_run = mn;
      #pragma unroll
      for (int dt = 0; dt < 4; ++dt) acc[dt] *= sc;
    }
    float ts[8];
    #pragma unroll
    for (int i = 0; i < 16; ++i) sv[i] = __expf(sv[i] - m_run);
    #pragma unroll
    for (int i = 0; i < 8; ++i) ts[i] = sv[i] + sv[i+8];
    #pragma unroll
    for (int st = 4; st > 0; st >>= 1)
      #pragma unroll
      for (int i = 0; i < st; ++i) ts[i] += ts[i+st];
    S_run += xsum64(ts[0]);

    // ---- P pack + permlane redistribute (T12, r7-verified) ----
    PW pw[2];
    #pragma unroll
    for (int b0 = 0; b0 < 2; ++b0) {
      U32H2 t0, t1, t2, t3;
      t0.h = __builtin_amdgcn_cvt_pkrtz(sv[8*b0+0], sv[8*b0+1]);
      t1.h = __builtin_amdgcn_cvt_pkrtz(sv[8*b0+2], sv[8*b0+3]);
      t2.h = __builtin_amdgcn_cvt_pkrtz(sv[8*b0+4], sv[8*b0+5]);
      t3.h = __builtin_amdgcn_cvt_pkrtz(sv[8*b0+6], sv[8*b0+7]);
      i32x2v r0 = __builtin_amdgcn_permlane32_swap((int)t0.u, (int)t2.u, false, false);
      i32x2v r1 = __builtin_amdgcn_permlane32_swap((int)t1.u, (int)t3.u, false, false);
      pw[b0].u[0] = (unsigned)r0[0];
      pw[b0].u[1] = (unsigned)r1[0];
      pw[b0].u[2] = (unsigned)r0[1];
      pw[b0].u[3] = (unsigned)r1[1];
    }

    // ---- PV^T: A = V^T (m=d), B = P (col=q). acc[dt]: row=d, col=q ----
    #pragma unroll
    for (int dt = 0; dt < 4; ++dt) {
      const int d    = dt*32 + l31;
      const int dRow = (d >> 1);
      const int dSub = d & 1;
      const int vswz = dRow & 15;
      const int vbase = 65536 + kvq*16384 + dRow*256;
      #pragma unroll
      for (int kb = 0; kb < 2; ++kb) {
        const int s = dSub*8 + ns*4 + kb*2 + hi;
        half8 vtf = *(const half8*)&POOL[vbase + ((s ^ vswz) << 4)];
        acc[dt] = __builtin_amdgcn_mfma_f32_32x32x16_f16(vtf, pw[kb].h, acc[dt], 0, 0, 0);
      }
    }

    __syncthreads();                       // barrier2: VT reads done
    if (!isK && t + 1 < NIT) stage(t + 1); // VT-DMA drains at next barrier0
  }

  // ---- two-stage exact combine: 8 streams -> 4 -> 1 per (wq, q) ----
  float* statsA = (float*)&POOL[SAOFF];
  float* statsB = (float*)&POOL[SBOFF];

  if (ns == 1) {  // stage 1 spill: regions r1 = kvq*2+wq, 16KB each
    float* base = (float*)&POOL[(kvq*2 + wq) * 16384];
    #pragma unroll
    for (int dt = 0; dt < 4; ++dt)
      #pragma unroll
      for (int rg = 0; rg < 4; ++rg) {
        const int j = dt*4 + rg;
        f32x4 v = {acc[dt][4*rg+0], acc[dt][4*rg+1], acc[dt][4*rg+2], acc[dt][4*rg+3]};
        *(f32x4*)&base[lane*64 + ((j ^ (lane & 15)) << 2)] = v;
      }
    if (lane < 32) {
      float* st = &statsA[((kvq*2 + wq)*32 + lane) * 4];
      st[0] = m_run; st[1] = S_run; st[2] = tmax;
    }
  }
  __syncthreads();

  if (ns == 0) {  // stage 1 merge
    const float* st = &statsA[((kvq*2 + wq)*32 + l31) * 4];
    const float m1 = st[0], S1 = st[1], t1 = st[2];
    const float M2 = fmaxf(m_run, m1);
    const float e0 = __expf(m_run - M2), e1 = __expf(m1 - M2);
    S_run = S_run * e0 + S1 * e1;
    tmax  = fmaxf(tmax, t1);
    m_run = M2;
    const float* base = (const float*)&POOL[(kvq*2 + wq) * 16384];
    #pragma unroll
    for (int dt = 0; dt < 4; ++dt)
      #pragma unroll
      for (int rg = 0; rg < 4; ++rg) {
        const int j = dt*4 + rg;
        const f32x4 pj = *(const f32x4*)&base[lane*64 + ((j ^ (lane & 15)) << 2)];
        #pragma unroll
        for (int i = 0; i < 4; ++i)
          acc[dt][4*rg+i] = acc[dt][4*rg+i] * e0 + pj[i] * e1;
      }
  }
  __syncthreads();

  if (ns == 0 && kvq != 0) {  // stage 2 spill: regions r2 = (kvq-1)*2+wq
    float* base = (float*)&POOL[((kvq - 1)*2 + wq) * 16384];
    #pragma unroll
    for (int dt = 0; dt < 4; ++dt)
      #pragma unroll
      for (int rg = 0; rg < 4; ++rg) {
        const int j = dt*4 + rg;
        f32x4 v = {acc[dt][4*rg+0], acc[dt][4*rg+1], acc[dt][4*rg+2], acc[dt][4*rg+3]};
        *(f32x4*)&base[lane*64 + ((j ^ (lane & 15)) << 2)] = v;
      }
    if (lane < 32) {
      float* st = &statsB[((kvq*2 + wq)*32 + lane) * 4];
      st[0] = m_run; st[1] = S_run; st[2] = tmax;
    }
  }
  __syncthreads();

  if (ns == 0 && kvq == 0) {  // final 4-way merge + epilogue
    float mj[4], Sj[4], tj[4];
    mj[0] = m_run; Sj[0] = S_run; tj[0] = tmax;
    #pragma unroll
    for (int j = 1; j < 4; ++j) {
      const float* st = &statsB[((j*2 + wq)*32 + l31) * 4];
      mj[j] = st[0]; Sj[j] = st[1]; tj[j] = st[2];
    }
    const float M = fmaxf(fmaxf(tj[0], tj[1]), fmaxf(tj[2], tj[3]));
    float fj[4], den = 0.f;
    #pragma unroll
    for (int j = 0; j < 4; ++j) { fj[j] = __expf(mj[j] - M); den += fj[j] * Sj[j]; }
    const float rs = rsqrtf(den);
    #pragma unroll
    for (int j = 0; j < 4; ++j) fj[j] *= rs;

    const int qrw = qb + wq*32 + l31;
    #pragma unroll
    for (int dt = 0; dt < 4; ++dt) {
      #pragma unroll
      for (int rg = 0; rg < 4; ++rg) {
        const int jj = dt*4 + rg;
        f32x4 av = {acc[dt][4*rg+0], acc[dt][4*rg+1], acc[dt][4*rg+2], acc[dt][4*rg+3]};
        av *= fj[0];
        #pragma unroll
        for (int j = 1; j < 4; ++j) {
          const float* base = (const float*)&POOL[((j - 1)*2 + wq) * 16384];
          const f32x4 pj = *(const f32x4*)&base[lane*64 + ((jj ^ (lane & 15)) << 2)];
          av += pj * fj[j];
        }
        const int d0 = dt*32 + rg*8 + hi*4;
        const float4 s = *(const float4*)&seqB[(size_t)qrw * DDIM + d0];
        float4 o;
        o.x = 0.5f * s.x * (1.f + av[0]);
        o.y = 0.5f * s.y * (1.f + av[1]);
        o.z = 0.5f * s.z * (1.f + av[2]);
        o.w = 0.5f * s.w * (1.f + av[3]);
        *(float4*)&outB[(size_t)qrw * DDIM + d0] = o;
      }
    }
  }
}

// ---------------- fallback (r7, proven): used if ws too small ----------------
__global__ __launch_bounds__(512, 2)
void gattn_fb(const float* __restrict__ seq, const float* __restrict__ fism,
              float* __restrict__ out)
{
  const int tid  = threadIdx.x;
  const int lane = tid & 63;
  const int wv   = tid >> 6;
  const int wq   = wv & 1;
  const int kvq  = wv >> 1;
  const int l31  = lane & 31;
  const int hi   = lane >> 5;

  const int swz = (blockIdx.x & 7) * 32 + (blockIdx.x >> 3);
  const int b   = swz >> 3;
  const int qb  = (swz & 7) * 64;

  const float* seqB = seq  + (size_t)b * LQ * DDIM;
  const float* fisB = fism + (size_t)b * NKV * DDIM;
  float*       outB = out  + (size_t)b * LQ * DDIM;

  __shared__ _Float16 Ksh[4][64 * DDIM];
  __shared__ _Float16 VTsh[4][(DDIM/2) * 128];
  __shared__ float    stats[4][2][32][3];

  half8 qf[8];
  {
    const int qrow = qb + wq * 32 + l31;
    #pragma unroll
    for (int c = 0; c < 8; ++c) {
      const float* p = seqB + (size_t)qrow * DDIM + c * 16 + hi * 8;
      float4 a  = *(const float4*)p;
      float4 b2 = *(const float4*)(p + 4);
      half8 h;
      h[0]=(_Float16)a.x;  h[1]=(_Float16)a.y;  h[2]=(_Float16)a.z;  h[3]=(_Float16)a.w;
      h[4]=(_Float16)b2.x; h[5]=(_Float16)b2.y; h[6]=(_Float16)b2.z; h[7]=(_Float16)b2.w;
      qf[c] = h;
    }
  }

  const int sp   = tid >> 3;
  const int dgrp = tid & 7;
  const int qstg = sp >> 4;
  const int spc  = sp & 15;

  f32x16 acc[4];
  #pragma unroll
  for (int dt = 0; dt < 4; ++dt)
    #pragma unroll
    for (int i = 0; i < 16; ++i) acc[dt][i] = 0.f;

  float m_run = -INFINITY, tmax = -INFINITY, S_run = 0.f;

  auto write_stage = [&](const float4* v) {
    #pragma unroll
    for (int r = 0; r < 4; ++r) {
      const int row = 4*spc + r;
      #pragma unroll
      for (int hh = 0; hh < 2; ++hh) {
        const float4 x = v[r*4 + hh*2];
        const float4 y = v[r*4 + hh*2 + 1];
        half8 h;
        h[0]=(_Float16)x.x; h[1]=(_Float16)x.y; h[2]=(_Float16)x.z; h[3]=(_Float16)x.w;
        h[4]=(_Float16)y.x; h[5]=(_Float16)y.y; h[6]=(_Float16)y.z; h[7]=(_Float16)y.w;
        const int idx = row*DDIM + ((dgrp*16 + hh*8) ^ (8*(row & 15)));
        *(half8*)&Ksh[qstg][idx] = h;
      }
    }
    #pragma unroll
    for (int k = 0; k < 16; ++k) {
      const int d = dgrp*16 + k;
      const int dRow = d >> 1, dSub = d & 1;
      half4v pk;
      #pragma unroll
      for (int r = 0; r < 4; ++r)
        pk[r] = (_Float16)(((const float*)&v[r*4 + (k>>2)])[k&3]);
      const int idx = dRow*128 + ((dSub*64 + 4*spc) ^ (8*(dRow & 15)));
      *(half4v*)&VTsh[qstg][idx] = pk;
    }
  };

  auto load_glb = [&](float4* v, int t) {
    const float* src = fisB + (size_t)(qstg*(NKV/4) + t*64) * DDIM;
    #pragma unroll
    for (int r = 0; r < 4; ++r)
      #pragma unroll
      for (int k = 0; k < 4; ++k)
        v[r*4+k] = *(const float4*)(src + (size_t)(4*spc + r)*DDIM + dgrp*16 + k*4);
  };

  {
    float4 stg[16];
    load_glb(stg, 0);
    write_stage(stg);
  }

  for (int t = 0; t < 8; ++t) {
    __syncthreads();
    float4 nxt[16];
    const bool have = (t + 1 < 8);
    if (have) load_glb(nxt, t + 1);

    f32x16 sv[2];
    #pragma unroll
    for (int nss = 0; nss < 2; ++nss) {
      f32x16 x;
      #pragma unroll
      for (int i = 0; i < 16; ++i) x[i] = 0.f;
      const int row = nss*32 + l31;
      const int sw  = 8*(row & 15);
      #pragma unroll
      for (int c = 0; c < 8; ++c) {
        const int idx = row*DDIM + ((c*16 + hi*8) ^ sw);
        half8 kf = *(const half8*)&Ksh[kvq][idx];
        x = __builtin_amdgcn_mfma_f32_32x32x16_f16(kf, qf[c], x, 0, 0, 0);
      }
      sv[nss] = x;
    }

    float mx[16];
    #pragma unroll
    for (int i = 0; i < 16; ++i) mx[i] = fmaxf(sv[0][i], sv[1][i]);
    #pragma unroll
    for (int st = 8; st > 0; st >>= 1)
      #pragma unroll
      for (int i = 0; i < st; ++i) mx[i] = fmaxf(mx[i], mx[i+st]);
    const float cmax = xmax64(mx[0]);
    tmax = fmaxf(tmax, cmax);
    if (__any(cmax > m_run + 8.f)) {
      const float mn = fmaxf(m_run, cmax);
      const float sc = __expf(m_run - mn);
      S_run *= sc;
      m_run = mn;
      #pragma unroll
      for (int dt = 0; dt < 4; ++dt) acc[dt] *= sc;
    }
    float ts[16];
    #pragma unroll
    for (int i = 0; i < 16; ++i) {
      const float p0 = __expf(sv[0][i] - m_run);
      const float p1 = __expf(sv[1][i] - m_run);
      sv[0][i] = p0; sv[1][i] = p1;
      ts[i] = p0 + p1;
    }
    #pragma unroll
    for (int st = 8; st > 0; st >>= 1)
      #pragma unroll
      for (int i = 0; i < st; ++i) ts[i] += ts[i+st];
    S_run += xsum64(ts[0]);

    PW pw[4];
    #pragma unroll
    for (int nss = 0; nss < 2; ++nss)
      #pragma unroll
      for (int b0 = 0; b0 < 2; ++b0) {
        U32H2 t0, t1, t2, t3;
        t0.h = __builtin_amdgcn_cvt_pkrtz(sv[nss][8*b0+0], sv[nss][8*b0+1]);
        t1.h = __builtin_amdgcn_cvt_pkrtz(sv[nss][8*b0+2], sv[nss][8*b0+3]);
        t2.h = __builtin_amdgcn_cvt_pkrtz(sv[nss][8*b0+4], sv[nss][8*b0+5]);
        t3.h = __builtin_amdgcn_cvt_pkrtz(sv[nss][8*b0+6], sv[nss][8*b0+7]);
        i32x2v r0 = __builtin_amdgcn_permlane32_swap((int)t0.u, (int)t2.u, false, false);
        i32x2v r1 = __builtin_amdgcn_permlane32_swap((int)t1.u, (int)t3.u, false, false);
        const int kb = 2*nss + b0;
        pw[kb].u[0] = (unsigned)r0[0];
        pw[kb].u[1] = (unsigned)r1[0];
        pw[kb].u[2] = (unsigned)r0[1];
        pw[kb].u[3] = (unsigned)r1[1];
      }

    #pragma unroll
    for (int dt = 0; dt < 4; ++dt) {
      const int d    = dt*32 + l31;
      const int dRow = d >> 1, dSub = d & 1;
      const int sw   = 8*(dRow & 15);
      #pragma unroll
      for (int kb = 0; kb < 4; ++kb) {
        const int idx = dRow*128 + ((dSub*64 + kb*16 + hi*8) ^ sw);
        half8 vtf = *(const half8*)&VTsh[kvq][idx];
        acc[dt] = __builtin_amdgcn_mfma_f32_32x32x16_f16(vtf, pw[kb].h, acc[dt], 0, 0, 0);
      }
    }

    __syncthreads();
    if (have) write_stage(nxt);
  }

  __syncthreads();

  float* Kf  = (float*)&Ksh[0][0];
  float* VTf = (float*)&VTsh[0][0];
  if (kvq != 0) {
    const int rgn = (kvq - 1) * 2 + wq;
    float* base = (rgn < 4) ? (Kf + rgn * 4096) : (VTf + (rgn - 4) * 4096);
    #pragma unroll
    for (int dt = 0; dt < 4; ++dt)
      #pragma unroll
      for (int rg = 0; rg < 4; ++rg) {
        f32x4 v = {acc[dt][4*rg+0], acc[dt][4*rg+1], acc[dt][4*rg+2], acc[dt][4*rg+3]};
        *(f32x4*)&base[lane*64 + (((dt*4+rg) ^ (lane & 15)) * 4)] = v;
      }
    if (lane < 32) {
      stats[kvq][wq][lane][0] = m_run;
      stats[kvq][wq][lane][1] = S_run;
      stats[kvq][wq][lane][2] = tmax;
    }
  }
  __syncthreads();

  if (kvq == 0) {
    float mj[4], Sj[4], tj[4];
    mj[0] = m_run; Sj[0] = S_run; tj[0] = tmax;
    #pragma unroll
    for (int j = 1; j < 4; ++j) {
      mj[j] = stats[j][wq][l31][0];
      Sj[j] = stats[j][wq][l31][1];
      tj[j] = stats[j][wq][l31][2];
    }
    const float M = fmaxf(fmaxf(tj[0], tj[1]), fmaxf(tj[2], tj[3]));
    float fj[4], den = 0.f;
    #pragma unroll
    for (int j = 0; j < 4; ++j) { fj[j] = __expf(mj[j] - M); den += fj[j] * Sj[j]; }
    const float rs = rsqrtf(den);
    #pragma unroll
    for (int j = 0; j < 4; ++j) fj[j] *= rs;

    const int qrow = qb + wq*32 + l31;
    #pragma unroll
    for (int dt = 0; dt < 4; ++dt) {
      #pragma unroll
      for (int rg = 0; rg < 4; ++rg) {
        f32x4 av = {acc[dt][4*rg+0], acc[dt][4*rg+1], acc[dt][4*rg+2], acc[dt][4*rg+3]};
        av *= fj[0];
        #pragma unroll
        for (int j = 1; j < 4; ++j) {
          const int rgn = (j - 1) * 2 + wq;
          const float* base = (rgn < 4) ? (Kf + rgn * 4096) : (VTf + (rgn - 4) * 4096);
          const f32x4 pj = *(const f32x4*)&base[lane*64 + (((dt*4+rg) ^ (lane & 15)) * 4)];
          av += pj * fj[j];
        }
        const int d0 = dt*32 + rg*8 + hi*4;
        const float4 s = *(const float4*)&seqB[(size_t)qrow * DDIM + d0];
        float4 o;
        o.x = 0.5f * s.x * (1.f + av[0]);
        o.y = 0.5f * s.y * (1.f + av[1]);
        o.z = 0.5f * s.z * (1.f + av[2]);
        o.w = 0.5f * s.w * (1.f + av[3]);
        *(float4*)&outB[(size_t)qrow * DDIM + d0] = o;
      }
    }
  }
}

extern "C" void kernel_launch(void* const* d_in, const int* in_sizes, int n_in,
                              void* d_out, int out_size, void* d_ws, size_t ws_size,
                              hipStream_t stream) {
  const float* seq  = (const float*)d_in[0];
  const float* fism = (const float*)d_in[1];
  float* out = (float*)d_out;
  if (ws_size >= 33554432ull) {
    _Float16* K16  = (_Float16*)d_ws;
    _Float16* VT16 = K16 + (size_t)NB * NKV * DDIM;
    prep<<<dim3(1024), dim3(256), 0, stream>>>(fism, K16, VT16);
    gattn<<<dim3(256), dim3(1024), 0, stream>>>(seq, K16, VT16, out);
  } else {
    gattn_fb<<<dim3(256), dim3(512), 0, stream>>>(seq, fism, out);
  }
}

// Round 9
// 60.753 us; speedup vs baseline: 1.4249x; 1.4249x over previous
//
#include <hip/hip_runtime.h>
#include <hip/hip_bf16.h>
#include <math.h>

typedef _Float16 half8  __attribute__((ext_vector_type(8)));
typedef _Float16 half4v __attribute__((ext_vector_type(4)));
typedef __fp16   fp16x2 __attribute__((ext_vector_type(2)));
typedef float    f32x4  __attribute__((ext_vector_type(4)));
typedef float    f32x16 __attribute__((ext_vector_type(16)));
typedef int      i32x2v __attribute__((ext_vector_type(2)));

#define DDIM 128
#define LQ   512
#define NKV  2048
#define NB   32
#define NIT  16

union U32H2 { unsigned u; fp16x2 h; };
union PW    { unsigned u[4]; half8 h; };

// permlane32_swap(a,b) -> ([a_lo|b_lo], [a_hi|b_hi])
__device__ __forceinline__ float xmax64(float v) {
  i32x2v r = __builtin_amdgcn_permlane32_swap(__float_as_int(v), __float_as_int(v), false, false);
  return fmaxf(__int_as_float(r[0]), __int_as_float(r[1]));
}
__device__ __forceinline__ float xsum64(float v) {
  i32x2v r = __builtin_amdgcn_permlane32_swap(__float_as_int(v), __float_as_int(v), false, false);
  return __int_as_float(r[0]) + __int_as_float(r[1]);
}

__device__ __forceinline__ void dma16(const void* g, void* l) {
  __builtin_amdgcn_global_load_lds(
      (const __attribute__((address_space(1))) unsigned int*)g,
      (__attribute__((address_space(3))) unsigned int*)l, 16, 0, 0);
}

// ---------------- prep: fism f32 -> K16 [b][kv][d] f16 and VT16 [b][d][kv] f16 ----------------
__global__ __launch_bounds__(256)
void prep(const float* __restrict__ fism, _Float16* __restrict__ K16,
          _Float16* __restrict__ VT16)
{
  __shared__ _Float16 T[64 * DDIM];
  const int tid = threadIdx.x;
  const int bb  = blockIdx.x >> 5;
  const int kv0 = (blockIdx.x & 31) * 64;
  {
    const int r  = tid >> 2;
    const int cq = tid & 3;
    const float* src = fism + ((size_t)(bb*NKV + kv0 + r) * DDIM + cq*32);
    _Float16*    kd  = K16  + ((size_t)(bb*NKV + kv0 + r) * DDIM + cq*32);
    float4 v[8];
    #pragma unroll
    for (int k = 0; k < 8; ++k) v[k] = ((const float4*)src)[k];
    _Float16 h[32];
    #pragma unroll
    for (int k = 0; k < 8; ++k) {
      h[4*k+0] = (_Float16)v[k].x; h[4*k+1] = (_Float16)v[k].y;
      h[4*k+2] = (_Float16)v[k].z; h[4*k+3] = (_Float16)v[k].w;
    }
    #pragma unroll
    for (int k = 0; k < 4; ++k) ((half8*)kd)[k] = *(half8*)&h[8*k];
    #pragma unroll
    for (int j = 0; j < 32; ++j) {
      const int d = cq*32 + j;
      T[d*64 + (((r>>3) ^ (d&7))<<3) + (r&7)] = h[j];
    }
  }
  __syncthreads();
  {
    const int d  = tid >> 1;
    const int kh = tid & 1;
    _Float16* vd = VT16 + ((size_t)(bb*DDIM + d) * NKV + kv0 + kh*32);
    #pragma unroll
    for (int u = 0; u < 4; ++u) {
      const int k8 = kh*4 + u;
      ((half8*)vd)[u] = *(half8*)&T[d*64 + ((k8 ^ (d&7))<<3)];
    }
  }
}

// ---------------- main: 4 waves (2 qg x 2 kv-halves), DMA staging, 2 blocks/CU ----------------
// POOL: Kh0 [0,16K), Kh1 [16K,32K), Vh0 [32K,48K), Vh1 [48K,64K)
__global__ __launch_bounds__(256, 2)
void gattn(const float* __restrict__ seq, const _Float16* __restrict__ K16,
           const _Float16* __restrict__ VT16, float* __restrict__ out)
{
  __shared__ __align__(16) unsigned char POOL[65536];
  __shared__ float stats[2][32][4];

  const int tid  = threadIdx.x;
  const int lane = tid & 63;
  const int wv   = tid >> 6;      // 0..3
  const int qg   = wv & 1;        // q-group (32 rows)
  const int kvh  = wv >> 1;       // KV half
  const int l31  = lane & 31;
  const int hi   = lane >> 5;

  const int swz = (blockIdx.x & 7) * 32 + (blockIdx.x >> 3);
  const int b   = swz >> 3;
  const int qb  = (swz & 7) * 64;

  const float* seqB = seq + (size_t)b * LQ * DDIM;
  float*       outB = out + (size_t)b * LQ * DDIM;
  const _Float16* K16b  = K16  + (size_t)b * NKV * DDIM;
  const _Float16* VT16b = VT16 + (size_t)b * DDIM * NKV;

  // ---- Q fragments in registers (B-frag: col=q=l31, k = c*16 + hi*8 + j) ----
  half8 qf[8];
  {
    const int qrow = qb + qg * 32 + l31;
    #pragma unroll
    for (int c = 0; c < 8; ++c) {
      const float* p = seqB + (size_t)qrow * DDIM + c * 16 + hi * 8;
      float4 a  = *(const float4*)p;
      float4 b2 = *(const float4*)(p + 4);
      half8 h;
      h[0]=(_Float16)a.x;  h[1]=(_Float16)a.y;  h[2]=(_Float16)a.z;  h[3]=(_Float16)a.w;
      h[4]=(_Float16)b2.x; h[5]=(_Float16)b2.y; h[6]=(_Float16)b2.z; h[7]=(_Float16)b2.w;
      qf[c] = h;
    }
  }

  // ---- DMA source offsets: wave wv stages one 16KB buffer (16 dma16/iter) ----
  const bool isK = (wv < 2);
  const int  hst = isK ? wv : (wv - 2);
  int off[16];
  #pragma unroll
  for (int i = 0; i < 16; ++i) {
    const int unit = i*64 + lane;
    const int r16 = unit >> 4, sp = unit & 15;
    const int s = sp ^ (r16 & 15);
    if (isK) {
      off[i] = r16*128 + s*8;
    } else {
      const int d = r16*2 + (s >> 3);
      off[i] = d*2048 + (s & 7)*8;
    }
  }
  const _Float16* sb0 = isK ? (K16b + (size_t)hst*1024*128) : (VT16b + hst*1024);
  const int tstr  = isK ? 8192 : 64;
  const int lbase = (isK ? 0 : 32768) + hst*16384;

  auto stage = [&](int tt) {
    const _Float16* s0 = sb0 + (size_t)tt * tstr;
    #pragma unroll
    for (int i = 0; i < 16; ++i)
      dma16(s0 + off[i], &POOL[lbase + i*1024]);
  };

  f32x16 acc[4];
  #pragma unroll
  for (int dt = 0; dt < 4; ++dt)
    #pragma unroll
    for (int i = 0; i < 16; ++i) acc[dt][i] = 0.f;

  float m_run = -INFINITY, tmax = -INFINITY, S_run = 0.f;

  stage(0);

  for (int t = 0; t < NIT; ++t) {
    __syncthreads();                       // b0: iter-t buffers landed

    // ---- QK^T: A=K (m=kv), B=Q (col=q). sv[ns]: row=kv, col=q=l31 ----
    f32x16 sv[2];
    __builtin_amdgcn_s_setprio(1);
    #pragma unroll
    for (int ns = 0; ns < 2; ++ns) {
      f32x16 x;
      #pragma unroll
      for (int i = 0; i < 16; ++i) x[i] = 0.f;
      const int krow = ns*32 + l31;
      const int kb_  = kvh*16384 + krow*256;
      const int ksw  = krow & 15;
      #pragma unroll
      for (int c = 0; c < 8; ++c) {
        const int u = 2*c + hi;
        half8 ka = *(const half8*)&POOL[kb_ + ((u ^ ksw) << 4)];
        x = __builtin_amdgcn_mfma_f32_32x32x16_f16(ka, qf[c], x, 0, 0, 0);
      }
      sv[ns] = x;
    }
    __builtin_amdgcn_s_setprio(0);

    __syncthreads();                       // b1: K reads done
    if (isK && t + 1 < NIT) stage(t + 1);  // K-DMA hides under softmax+PV

    // ---- online power-softmax (lane-local, col=q) ----
    float mx[16];
    #pragma unroll
    for (int i = 0; i < 16; ++i) mx[i] = fmaxf(sv[0][i], sv[1][i]);
    #pragma unroll
    for (int st = 8; st > 0; st >>= 1)
      #pragma unroll
      for (int i = 0; i < st; ++i) mx[i] = fmaxf(mx[i], mx[i+st]);
    const float cmax = xmax64(mx[0]);
    tmax = fmaxf(tmax, cmax);
    if (__any(cmax > m_run + 8.f)) {
      const float mn = fmaxf(m_run, cmax);
      const float sc = __expf(m_run - mn);
      S_run *= sc;
      m_run = mn;
      #pragma unroll
      for (int dt = 0; dt < 4; ++dt) acc[dt] *= sc;
    }
    float ts[16];
    #pragma unroll
    for (int i = 0; i < 16; ++i) {
      const float p0 = __expf(sv[0][i] - m_run);
      const float p1 = __expf(sv[1][i] - m_run);
      sv[0][i] = p0; sv[1][i] = p1;
      ts[i] = p0 + p1;
    }
    #pragma unroll
    for (int st = 8; st > 0; st >>= 1)
      #pragma unroll
      for (int i = 0; i < st; ++i) ts[i] += ts[i+st];
    S_run += xsum64(ts[0]);

    // ---- P pack + permlane redistribute (T12, r7-verified) ----
    PW pw[4];
    #pragma unroll
    for (int nss = 0; nss < 2; ++nss)
      #pragma unroll
      for (int b0 = 0; b0 < 2; ++b0) {
        U32H2 t0, t1, t2, t3;
        t0.h = __builtin_amdgcn_cvt_pkrtz(sv[nss][8*b0+0], sv[nss][8*b0+1]);
        t1.h = __builtin_amdgcn_cvt_pkrtz(sv[nss][8*b0+2], sv[nss][8*b0+3]);
        t2.h = __builtin_amdgcn_cvt_pkrtz(sv[nss][8*b0+4], sv[nss][8*b0+5]);
        t3.h = __builtin_amdgcn_cvt_pkrtz(sv[nss][8*b0+6], sv[nss][8*b0+7]);
        i32x2v r0 = __builtin_amdgcn_permlane32_swap((int)t0.u, (int)t2.u, false, false);
        i32x2v r1 = __builtin_amdgcn_permlane32_swap((int)t1.u, (int)t3.u, false, false);
        const int kb = 2*nss + b0;
        pw[kb].u[0] = (unsigned)r0[0];
        pw[kb].u[1] = (unsigned)r1[0];
        pw[kb].u[2] = (unsigned)r0[1];
        pw[kb].u[3] = (unsigned)r1[1];
      }

    // ---- PV^T: A=V^T (m=d), B=P (col=q). acc[dt]: row=d, col=q ----
    __builtin_amdgcn_s_setprio(1);
    #pragma unroll
    for (int dt = 0; dt < 4; ++dt) {
      const int d    = dt*32 + l31;
      const int dRow = d >> 1, dSub = d & 1;
      const int vsw  = dRow & 15;
      const int vb   = 32768 + kvh*16384 + dRow*256;
      #pragma unroll
      for (int kb = 0; kb < 4; ++kb) {
        const int u = dSub*8 + kb*2 + hi;
        half8 vtf = *(const half8*)&POOL[vb + ((u ^ vsw) << 4)];
        acc[dt] = __builtin_amdgcn_mfma_f32_32x32x16_f16(vtf, pw[kb].h, acc[dt], 0, 0, 0);
      }
    }
    __builtin_amdgcn_s_setprio(0);

    __syncthreads();                       // b2: V reads done
    if (!isK && t + 1 < NIT) stage(t + 1); // V-DMA drains at next b0
  }

  __syncthreads();

  // ---- 2-way exact combine ----
  if (kvh == 1) {
    float* base = (float*)&POOL[qg * 16384];
    #pragma unroll
    for (int dt = 0; dt < 4; ++dt)
      #pragma unroll
      for (int rg = 0; rg < 4; ++rg) {
        const int j = dt*4 + rg;
        f32x4 v = {acc[dt][4*rg+0], acc[dt][4*rg+1], acc[dt][4*rg+2], acc[dt][4*rg+3]};
        *(f32x4*)&base[lane*64 + ((j ^ (lane & 15)) << 2)] = v;
      }
    if (lane < 32) {
      stats[qg][lane][0] = m_run;
      stats[qg][lane][1] = S_run;
      stats[qg][lane][2] = tmax;
    }
  }
  __syncthreads();

  if (kvh == 0) {
    const float m1 = stats[qg][l31][0];
    const float S1 = stats[qg][l31][1];
    const float t1 = stats[qg][l31][2];
    const float M2 = fmaxf(m_run, m1);
    const float e0 = __expf(m_run - M2), e1 = __expf(m1 - M2);
    const float S  = S_run * e0 + S1 * e1;
    const float T  = fmaxf(tmax, t1);
    const float fs = __expf(0.5f * (M2 - T)) * rsqrtf(S);  // per-lane (col=q)

    const float* base = (const float*)&POOL[qg * 16384];
    const int qrw = qb + qg*32 + l31;
    #pragma unroll
    for (int dt = 0; dt < 4; ++dt) {
      #pragma unroll
      for (int rg = 0; rg < 4; ++rg) {
        const int j = dt*4 + rg;
        const f32x4 pj = *(const f32x4*)&base[lane*64 + ((j ^ (lane & 15)) << 2)];
        f32x4 av;
        #pragma unroll
        for (int i = 0; i < 4; ++i)
          av[i] = (acc[dt][4*rg+i] * e0 + pj[i] * e1) * fs;
        const int d0 = dt*32 + rg*8 + hi*4;
        const float4 s = *(const float4*)&seqB[(size_t)qrw * DDIM + d0];
        float4 o;
        o.x = 0.5f * s.x * (1.f + av[0]);
        o.y = 0.5f * s.y * (1.f + av[1]);
        o.z = 0.5f * s.z * (1.f + av[2]);
        o.w = 0.5f * s.w * (1.f + av[3]);
        *(float4*)&outB[(size_t)qrw * DDIM + d0] = o;
      }
    }
  }
}

// ---------------- fallback (r7, proven): used if ws too small ----------------
__global__ __launch_bounds__(512, 2)
void gattn_fb(const float* __restrict__ seq, const float* __restrict__ fism,
              float* __restrict__ out)
{
  const int tid  = threadIdx.x;
  const int lane = tid & 63;
  const int wv   = tid >> 6;
  const int wq   = wv & 1;
  const int kvq  = wv >> 1;
  const int l31  = lane & 31;
  const int hi   = lane >> 5;

  const int swz = (blockIdx.x & 7) * 32 + (blockIdx.x >> 3);
  const int b   = swz >> 3;
  const int qb  = (swz & 7) * 64;

  const float* seqB = seq  + (size_t)b * LQ * DDIM;
  const float* fisB = fism + (size_t)b * NKV * DDIM;
  float*       outB = out  + (size_t)b * LQ * DDIM;

  __shared__ _Float16 Ksh[4][64 * DDIM];
  __shared__ _Float16 VTsh[4][(DDIM/2) * 128];
  __shared__ float    stats[4][2][32][3];

  half8 qf[8];
  {
    const int qrow = qb + wq * 32 + l31;
    #pragma unroll
    for (int c = 0; c < 8; ++c) {
      const float* p = seqB + (size_t)qrow * DDIM + c * 16 + hi * 8;
      float4 a  = *(const float4*)p;
      float4 b2 = *(const float4*)(p + 4);
      half8 h;
      h[0]=(_Float16)a.x;  h[1]=(_Float16)a.y;  h[2]=(_Float16)a.z;  h[3]=(_Float16)a.w;
      h[4]=(_Float16)b2.x; h[5]=(_Float16)b2.y; h[6]=(_Float16)b2.z; h[7]=(_Float16)b2.w;
      qf[c] = h;
    }
  }

  const int sp   = tid >> 3;
  const int dgrp = tid & 7;
  const int qstg = sp >> 4;
  const int spc  = sp & 15;

  f32x16 acc[4];
  #pragma unroll
  for (int dt = 0; dt < 4; ++dt)
    #pragma unroll
    for (int i = 0; i < 16; ++i) acc[dt][i] = 0.f;

  float m_run = -INFINITY, tmax = -INFINITY, S_run = 0.f;

  auto write_stage = [&](const float4* v) {
    #pragma unroll
    for (int r = 0; r < 4; ++r) {
      const int row = 4*spc + r;
      #pragma unroll
      for (int hh = 0; hh < 2; ++hh) {
        const float4 x = v[r*4 + hh*2];
        const float4 y = v[r*4 + hh*2 + 1];
        half8 h;
        h[0]=(_Float16)x.x; h[1]=(_Float16)x.y; h[2]=(_Float16)x.z; h[3]=(_Float16)x.w;
        h[4]=(_Float16)y.x; h[5]=(_Float16)y.y; h[6]=(_Float16)y.z; h[7]=(_Float16)y.w;
        const int idx = row*DDIM + ((dgrp*16 + hh*8) ^ (8*(row & 15)));
        *(half8*)&Ksh[qstg][idx] = h;
      }
    }
    #pragma unroll
    for (int k = 0; k < 16; ++k) {
      const int d = dgrp*16 + k;
      const int dRow = d >> 1, dSub = d & 1;
      half4v pk;
      #pragma unroll
      for (int r = 0; r < 4; ++r)
        pk[r] = (_Float16)(((const float*)&v[r*4 + (k>>2)])[k&3]);
      const int idx = dRow*128 + ((dSub*64 + 4*spc) ^ (8*(dRow & 15)));
      *(half4v*)&VTsh[qstg][idx] = pk;
    }
  };

  auto load_glb = [&](float4* v, int t) {
    const float* src = fisB + (size_t)(qstg*(NKV/4) + t*64) * DDIM;
    #pragma unroll
    for (int r = 0; r < 4; ++r)
      #pragma unroll
      for (int k = 0; k < 4; ++k)
        v[r*4+k] = *(const float4*)(src + (size_t)(4*spc + r)*DDIM + dgrp*16 + k*4);
  };

  {
    float4 stg[16];
    load_glb(stg, 0);
    write_stage(stg);
  }

  for (int t = 0; t < 8; ++t) {
    __syncthreads();
    float4 nxt[16];
    const bool have = (t + 1 < 8);
    if (have) load_glb(nxt, t + 1);

    f32x16 sv[2];
    #pragma unroll
    for (int nss = 0; nss < 2; ++nss) {
      f32x16 x;
      #pragma unroll
      for (int i = 0; i < 16; ++i) x[i] = 0.f;
      const int row = nss*32 + l31;
      const int sw  = 8*(row & 15);
      #pragma unroll
      for (int c = 0; c < 8; ++c) {
        const int idx = row*DDIM + ((c*16 + hi*8) ^ sw);
        half8 kf = *(const half8*)&Ksh[kvq][idx];
        x = __builtin_amdgcn_mfma_f32_32x32x16_f16(kf, qf[c], x, 0, 0, 0);
      }
      sv[nss] = x;
    }

    float mx[16];
    #pragma unroll
    for (int i = 0; i < 16; ++i) mx[i] = fmaxf(sv[0][i], sv[1][i]);
    #pragma unroll
    for (int st = 8; st > 0; st >>= 1)
      #pragma unroll
      for (int i = 0; i < st; ++i) mx[i] = fmaxf(mx[i], mx[i+st]);
    const float cmax = xmax64(mx[0]);
    tmax = fmaxf(tmax, cmax);
    if (__any(cmax > m_run + 8.f)) {
      const float mn = fmaxf(m_run, cmax);
      const float sc = __expf(m_run - mn);
      S_run *= sc;
      m_run = mn;
      #pragma unroll
      for (int dt = 0; dt < 4; ++dt) acc[dt] *= sc;
    }
    float ts[16];
    #pragma unroll
    for (int i = 0; i < 16; ++i) {
      const float p0 = __expf(sv[0][i] - m_run);
      const float p1 = __expf(sv[1][i] - m_run);
      sv[0][i] = p0; sv[1][i] = p1;
      ts[i] = p0 + p1;
    }
    #pragma unroll
    for (int st = 8; st > 0; st >>= 1)
      #pragma unroll
      for (int i = 0; i < st; ++i) ts[i] += ts[i+st];
    S_run += xsum64(ts[0]);

    PW pw[4];
    #pragma unroll
    for (int nss = 0; nss < 2; ++nss)
      #pragma unroll
      for (int b0 = 0; b0 < 2; ++b0) {
        U32H2 t0, t1, t2, t3;
        t0.h = __builtin_amdgcn_cvt_pkrtz(sv[nss][8*b0+0], sv[nss][8*b0+1]);
        t1.h = __builtin_amdgcn_cvt_pkrtz(sv[nss][8*b0+2], sv[nss][8*b0+3]);
        t2.h = __builtin_amdgcn_cvt_pkrtz(sv[nss][8*b0+4], sv[nss][8*b0+5]);
        t3.h = __builtin_amdgcn_cvt_pkrtz(sv[nss][8*b0+6], sv[nss][8*b0+7]);
        i32x2v r0 = __builtin_amdgcn_permlane32_swap((int)t0.u, (int)t2.u, false, false);
        i32x2v r1 = __builtin_amdgcn_permlane32_swap((int)t1.u, (int)t3.u, false, false);
        const int kb = 2*nss + b0;
        pw[kb].u[0] = (unsigned)r0[0];
        pw[kb].u[1] = (unsigned)r1[0];
        pw[kb].u[2] = (unsigned)r0[1];
        pw[kb].u[3] = (unsigned)r1[1];
      }

    #pragma unroll
    for (int dt = 0; dt < 4; ++dt) {
      const int d    = dt*32 + l31;
      const int dRow = d >> 1, dSub = d & 1;
      const int sw   = 8*(dRow & 15);
      #pragma unroll
      for (int kb = 0; kb < 4; ++kb) {
        const int idx = dRow*128 + ((dSub*64 + kb*16 + hi*8) ^ sw);
        half8 vtf = *(const half8*)&VTsh[kvq][idx];
        acc[dt] = __builtin_amdgcn_mfma_f32_32x32x16_f16(vtf, pw[kb].h, acc[dt], 0, 0, 0);
      }
    }

    __syncthreads();
    if (have) write_stage(nxt);
  }

  __syncthreads();

  float* Kf  = (float*)&Ksh[0][0];
  float* VTf = (float*)&VTsh[0][0];
  if (kvq != 0) {
    const int rgn = (kvq - 1) * 2 + wq;
    float* base = (rgn < 4) ? (Kf + rgn * 4096) : (VTf + (rgn - 4) * 4096);
    #pragma unroll
    for (int dt = 0; dt < 4; ++dt)
      #pragma unroll
      for (int rg = 0; rg < 4; ++rg) {
        f32x4 v = {acc[dt][4*rg+0], acc[dt][4*rg+1], acc[dt][4*rg+2], acc[dt][4*rg+3]};
        *(f32x4*)&base[lane*64 + (((dt*4+rg) ^ (lane & 15)) * 4)] = v;
      }
    if (lane < 32) {
      stats[kvq][wq][lane][0] = m_run;
      stats[kvq][wq][lane][1] = S_run;
      stats[kvq][wq][lane][2] = tmax;
    }
  }
  __syncthreads();

  if (kvq == 0) {
    float mj[4], Sj[4], tj[4];
    mj[0] = m_run; Sj[0] = S_run; tj[0] = tmax;
    #pragma unroll
    for (int j = 1; j < 4; ++j) {
      mj[j] = stats[j][wq][l31][0];
      Sj[j] = stats[j][wq][l31][1];
      tj[j] = stats[j][wq][l31][2];
    }
    const float M = fmaxf(fmaxf(tj[0], tj[1]), fmaxf(tj[2], tj[3]));
    float fj[4], den = 0.f;
    #pragma unroll
    for (int j = 0; j < 4; ++j) { fj[j] = __expf(mj[j] - M); den += fj[j] * Sj[j]; }
    const float rs = rsqrtf(den);
    #pragma unroll
    for (int j = 0; j < 4; ++j) fj[j] *= rs;

    const int qrow = qb + wq*32 + l31;
    #pragma unroll
    for (int dt = 0; dt < 4; ++dt) {
      #pragma unroll
      for (int rg = 0; rg < 4; ++rg) {
        f32x4 av = {acc[dt][4*rg+0], acc[dt][4*rg+1], acc[dt][4*rg+2], acc[dt][4*rg+3]};
        av *= fj[0];
        #pragma unroll
        for (int j = 1; j < 4; ++j) {
          const int rgn = (j - 1) * 2 + wq;
          const float* base = (rgn < 4) ? (Kf + rgn * 4096) : (VTf + (rgn - 4) * 4096);
          const f32x4 pj = *(const f32x4*)&base[lane*64 + (((dt*4+rg) ^ (lane & 15)) * 4)];
          av += pj * fj[j];
        }
        const int d0 = dt*32 + rg*8 + hi*4;
        const float4 s = *(const float4*)&seqB[(size_t)qrow * DDIM + d0];
        float4 o;
        o.x = 0.5f * s.x * (1.f + av[0]);
        o.y = 0.5f * s.y * (1.f + av[1]);
        o.z = 0.5f * s.z * (1.f + av[2]);
        o.w = 0.5f * s.w * (1.f + av[3]);
        *(float4*)&outB[(size_t)qrow * DDIM + d0] = o;
      }
    }
  }
}

extern "C" void kernel_launch(void* const* d_in, const int* in_sizes, int n_in,
                              void* d_out, int out_size, void* d_ws, size_t ws_size,
                              hipStream_t stream) {
  const float* seq  = (const float*)d_in[0];
  const float* fism = (const float*)d_in[1];
  float* out = (float*)d_out;
  if (ws_size >= 33554432ull) {
    _Float16* K16  = (_Float16*)d_ws;
    _Float16* VT16 = K16 + (size_t)NB * NKV * DDIM;
    prep<<<dim3(1024), dim3(256), 0, stream>>>(fism, K16, VT16);
    gattn<<<dim3(256), dim3(256), 0, stream>>>(seq, K16, VT16, out);
  } else {
    gattn_fb<<<dim3(256), dim3(512), 0, stream>>>(seq, fism, out);
  }
}